// Round 3
// baseline (988.624 us; speedup 1.0000x reference)
//
#include <hip/hip_runtime.h>

// VertexUpdate: out[i] = (b_i, x_i, b_i - sum_{e:src[e]=i} c_e)
// Round-1 finding: device-scope fp32 atomics write through past per-XCD L2
// (WRITE_SIZE = 16M x 32B = 500 MB, 21 G atomic/s cap -> 771 us).
// Design: per-XCD privatized replicas (8 x 4 MB in d_ws) + WORKGROUP-scope
// atomics (no sc1 -> cached RMW in the local TCC). A block never leaves its
// XCD; s_getreg(HW_REG_XCC_ID) identifies it (learn_hip m09). Final kernel
// sums the 8 replicas and writes (b, x, b - sum).
// Round-2 fix: __builtin_nontemporal_load needs native clang vectors, not
// HIP's int4/float4 wrapper classes -> ext_vector_type typedefs.

#define NREP 8

typedef int   vint4   __attribute__((ext_vector_type(4)));
typedef float vfloat4 __attribute__((ext_vector_type(4)));

__device__ __forceinline__ int xcc_id() {
    // s_getreg_b32 hwreg(id=HW_REG_XCC_ID(20), offset=0, size=4)
    // imm = (size-1)<<11 | offset<<6 | id = (3<<11) | 20
    return (int)(__builtin_amdgcn_s_getreg((3 << 11) | 20) & 7);
}

__global__ void vu_scatter_rep(const int* __restrict__ src,
                               const float* __restrict__ eattr,
                               float* __restrict__ reps, int ne, int nv) {
    float* rep = reps + (size_t)xcc_id() * (size_t)nv;
    int t = blockIdx.x * blockDim.x + threadIdx.x;
    int e0 = t * 4;
    if (e0 + 3 < ne) {
        vint4   idx = __builtin_nontemporal_load((const vint4*)src + t);
        vfloat4 a   = __builtin_nontemporal_load((const vfloat4*)eattr + 2 * t + 0);
        vfloat4 b   = __builtin_nontemporal_load((const vfloat4*)eattr + 2 * t + 1);
        __hip_atomic_fetch_add(&rep[idx.x], a.y, __ATOMIC_RELAXED, __HIP_MEMORY_SCOPE_WORKGROUP);
        __hip_atomic_fetch_add(&rep[idx.y], a.w, __ATOMIC_RELAXED, __HIP_MEMORY_SCOPE_WORKGROUP);
        __hip_atomic_fetch_add(&rep[idx.z], b.y, __ATOMIC_RELAXED, __HIP_MEMORY_SCOPE_WORKGROUP);
        __hip_atomic_fetch_add(&rep[idx.w], b.w, __ATOMIC_RELAXED, __HIP_MEMORY_SCOPE_WORKGROUP);
    } else {
        for (int e = e0; e < ne; ++e) {
            __hip_atomic_fetch_add(&rep[src[e]], eattr[2 * e + 1],
                                   __ATOMIC_RELAXED, __HIP_MEMORY_SCOPE_WORKGROUP);
        }
    }
}

__global__ void vu_reduce(const float* __restrict__ vattr,
                          const float* __restrict__ reps,
                          float* __restrict__ out, int nv) {
    int i = blockIdx.x * blockDim.x + threadIdx.x;
    if (i < nv) {
        float s = 0.0f;
#pragma unroll
        for (int r = 0; r < NREP; ++r) s += reps[(size_t)r * nv + i];
        float2 v = ((const float2*)vattr)[i];
        out[3 * i + 0] = v.x;
        out[3 * i + 1] = v.y;
        out[3 * i + 2] = v.x - s;
    }
}

// ---- fallback (round-1 path) if ws is too small ----
__global__ void vu_init_kernel(const float* __restrict__ vattr,
                               float* __restrict__ out, int n) {
    int i = blockIdx.x * blockDim.x + threadIdx.x;
    if (i < n) {
        float2 v = ((const float2*)vattr)[i];
        out[3 * i + 0] = v.x;
        out[3 * i + 1] = v.y;
        out[3 * i + 2] = v.x;
    }
}

__global__ void vu_scatter_kernel(const int* __restrict__ src,
                                  const float* __restrict__ eattr,
                                  float* __restrict__ out, int ne) {
    int t = blockIdx.x * blockDim.x + threadIdx.x;
    int e0 = t * 4;
    if (e0 + 3 < ne) {
        int4 idx = ((const int4*)src)[t];
        float4 a = ((const float4*)eattr)[2 * t + 0];
        float4 b = ((const float4*)eattr)[2 * t + 1];
        atomicAdd(&out[3 * idx.x + 2], -a.y);
        atomicAdd(&out[3 * idx.y + 2], -a.w);
        atomicAdd(&out[3 * idx.z + 2], -b.y);
        atomicAdd(&out[3 * idx.w + 2], -b.w);
    } else {
        for (int e = e0; e < ne; ++e) {
            atomicAdd(&out[3 * src[e] + 2], -eattr[2 * e + 1]);
        }
    }
}

extern "C" void kernel_launch(void* const* d_in, const int* in_sizes, int n_in,
                              void* d_out, int out_size, void* d_ws, size_t ws_size,
                              hipStream_t stream) {
    const float* vattr = (const float*)d_in[0];
    const int* edges = (const int*)d_in[1];   // (2, N_E); row 0 = src
    const float* eattr = (const float*)d_in[2];
    float* out = (float*)d_out;

    int nv = in_sizes[0] / 2;   // 1,000,000
    int ne = in_sizes[2] / 2;   // 16,000,000

    size_t need = (size_t)NREP * (size_t)nv * sizeof(float);  // 32 MB

    if (ws_size >= need) {
        float* reps = (float*)d_ws;
        (void)hipMemsetAsync(reps, 0, need, stream);
        {
            int threads = 256;
            int nt = (ne + 3) / 4;
            int blocks = (nt + threads - 1) / threads;
            vu_scatter_rep<<<blocks, threads, 0, stream>>>(edges, eattr, reps, ne, nv);
        }
        {
            int threads = 256;
            int blocks = (nv + threads - 1) / threads;
            vu_reduce<<<blocks, threads, 0, stream>>>(vattr, reps, out, nv);
        }
    } else {
        int threads = 256;
        int blocks = (nv + threads - 1) / threads;
        vu_init_kernel<<<blocks, threads, 0, stream>>>(vattr, out, nv);
        int nt = (ne + 3) / 4;
        blocks = (nt + threads - 1) / threads;
        vu_scatter_kernel<<<blocks, threads, 0, stream>>>(edges, eattr, out, ne);
    }
}

// Round 4
// 639.877 us; speedup vs baseline: 1.5450x; 1.5450x over previous
//
#include <hip/hip_runtime.h>

// VertexUpdate: out[i] = (b_i, x_i, b_i - sum_{e:src[e]=i} c_e)
//
// R1: device atomicAdd scatter -> 771 us, WRITE_SIZE 500 MB (16M x 32B).
// R3: per-XCD replicas + workgroup-scope atomics -> IDENTICAL counters.
//     Conclusion: atomics RMW in local TCC but miss L2 ~100% (replica 4 MB =
//     whole per-XCD L2, evicted by the 192 MB edge stream before reuse; avg
//     reuse distance 1M edges). Bound by atomic-miss pipe ~21 G/s, not BW.
// R4: two-pass radix binning. Bucket = src >> 11 (2048 verts, 489 buckets).
//     Pass 1 partitions edges into per-bucket regions (streaming + LDS
//     atomics only). Pass 2: one block per bucket, LDS acc[2048] (8 KB),
//     LDS atomicAdd, direct output write. Zero global fp atomics.

#define BSHIFT 11
#define BSIZE (1 << BSHIFT)
#define CHUNK 32768

__global__ void vu_partition(const int* __restrict__ src,
                             const float* __restrict__ eattr,
                             unsigned long long* __restrict__ pairs,
                             unsigned int* __restrict__ alloc,
                             int ne, int nbuck, int cap) {
    extern __shared__ unsigned int lds[];  // hist[nbuck] ++ cursor[nbuck]
    unsigned int* hist = lds;
    unsigned int* cursor = lds + nbuck;
    int t = threadIdx.x;
    for (int q = t; q < nbuck; q += blockDim.x) hist[q] = 0u;
    __syncthreads();

    int base = blockIdx.x * CHUNK;
    int lim = ne - base; if (lim > CHUNK) lim = CHUNK;

    // sweep 1: block-local histogram (LDS atomics)
    for (int i = t; i < lim; i += 256) {
        int s = src[base + i];
        atomicAdd(&hist[s >> BSHIFT], 1u);
    }
    __syncthreads();

    // reserve contiguous space in each bucket region (one global atomic per
    // bucket per block: ~489*489 = 239K total, amortized across the kernel)
    for (int q = t; q < nbuck; q += blockDim.x) {
        unsigned int h = hist[q];
        unsigned int start = h ? atomicAdd(&alloc[q], h) : 0u;
        cursor[q] = (unsigned int)q * (unsigned int)cap + start;
    }
    __syncthreads();

    // sweep 2: re-read (src L2-hot) and scatter packed (idx, cbits) words
    for (int i = t; i < lim; i += 256) {
        int e = base + i;
        int s = src[e];
        float2 ec = ((const float2*)eattr)[e];  // .y = c_ij
        int q = s >> BSHIFT;
        unsigned int slot = atomicAdd(&cursor[q], 1u);
        unsigned int hi = (unsigned int)q * (unsigned int)cap + (unsigned int)cap - 1u;
        if (slot > hi) slot = hi;  // statistically impossible; OOB guard
        unsigned long long p =
            ((unsigned long long)__float_as_uint(ec.y) << 32) | (unsigned int)s;
        pairs[slot] = p;
    }
}

__global__ void vu_aggregate(const unsigned long long* __restrict__ pairs,
                             const unsigned int* __restrict__ alloc,
                             const float* __restrict__ vattr,
                             float* __restrict__ out,
                             int nv, int cap) {
    __shared__ float acc[BSIZE];
    int q = blockIdx.x;
    int t = threadIdx.x;
    for (int i = t; i < BSIZE; i += blockDim.x) acc[i] = 0.0f;
    __syncthreads();

    unsigned int cnt = alloc[q];
    if (cnt > (unsigned int)cap) cnt = (unsigned int)cap;
    const unsigned long long* p = pairs + (size_t)q * (size_t)cap;
    for (unsigned int i = t; i < cnt; i += blockDim.x) {
        unsigned long long v = p[i];
        int s = (int)(unsigned int)(v & 0xffffffffu);
        float c = __uint_as_float((unsigned int)(v >> 32));
        atomicAdd(&acc[s & (BSIZE - 1)], c);
    }
    __syncthreads();

    int v0 = q << BSHIFT;
    for (int i = t; i < BSIZE; i += blockDim.x) {
        int v = v0 + i;
        if (v < nv) {
            float2 va = ((const float2*)vattr)[v];  // .x=b, .y=x
            out[3 * v + 0] = va.x;
            out[3 * v + 1] = va.y;
            out[3 * v + 2] = va.x - acc[i];
        }
    }
}

// ---- fallback (round-1 path, passed at 961 us) if ws is too small ----
__global__ void vu_init_kernel(const float* __restrict__ vattr,
                               float* __restrict__ out, int n) {
    int i = blockIdx.x * blockDim.x + threadIdx.x;
    if (i < n) {
        float2 v = ((const float2*)vattr)[i];
        out[3 * i + 0] = v.x;
        out[3 * i + 1] = v.y;
        out[3 * i + 2] = v.x;
    }
}

__global__ void vu_scatter_kernel(const int* __restrict__ src,
                                  const float* __restrict__ eattr,
                                  float* __restrict__ out, int ne) {
    int t = blockIdx.x * blockDim.x + threadIdx.x;
    int e0 = t * 4;
    if (e0 + 3 < ne) {
        int4 idx = ((const int4*)src)[t];
        float4 a = ((const float4*)eattr)[2 * t + 0];
        float4 b = ((const float4*)eattr)[2 * t + 1];
        atomicAdd(&out[3 * idx.x + 2], -a.y);
        atomicAdd(&out[3 * idx.y + 2], -a.w);
        atomicAdd(&out[3 * idx.z + 2], -b.y);
        atomicAdd(&out[3 * idx.w + 2], -b.w);
    } else {
        for (int e = e0; e < ne; ++e)
            atomicAdd(&out[3 * src[e] + 2], -eattr[2 * e + 1]);
    }
}

extern "C" void kernel_launch(void* const* d_in, const int* in_sizes, int n_in,
                              void* d_out, int out_size, void* d_ws, size_t ws_size,
                              hipStream_t stream) {
    const float* vattr = (const float*)d_in[0];
    const int* edges = (const int*)d_in[1];   // (2, N_E); row 0 = src
    const float* eattr = (const float*)d_in[2];
    float* out = (float*)d_out;

    int nv = in_sizes[0] / 2;   // 1,000,000
    int ne = in_sizes[2] / 2;   // 16,000,000

    int nbuck = (nv + BSIZE - 1) >> BSHIFT;          // 489
    int mean = ne / nbuck;                           // ~32.7K
    int cap = mean + mean / 8 + 1024;                // +~13% slack
    cap = (cap + 15) & ~15;

    size_t alloc_bytes = 4096;                        // counters, aligned pad
    size_t pair_bytes = (size_t)nbuck * (size_t)cap * 8ull;
    size_t need = alloc_bytes + pair_bytes;           // ~145 MB

    if (ws_size >= need && (size_t)nbuck * 4 <= alloc_bytes) {
        unsigned int* alloc = (unsigned int*)d_ws;
        unsigned long long* pairs = (unsigned long long*)((char*)d_ws + alloc_bytes);
        (void)hipMemsetAsync(alloc, 0, (size_t)nbuck * 4, stream);

        int p1_blocks = (ne + CHUNK - 1) / CHUNK;     // 489
        size_t lds = (size_t)nbuck * 2 * sizeof(unsigned int);
        vu_partition<<<p1_blocks, 256, lds, stream>>>(edges, eattr, pairs, alloc,
                                                      ne, nbuck, cap);
        vu_aggregate<<<nbuck, 256, 0, stream>>>(pairs, alloc, vattr, out, nv, cap);
    } else {
        int threads = 256;
        int blocks = (nv + threads - 1) / threads;
        vu_init_kernel<<<blocks, threads, 0, stream>>>(vattr, out, nv);
        int nt = (ne + 3) / 4;
        blocks = (nt + threads - 1) / threads;
        vu_scatter_kernel<<<blocks, threads, 0, stream>>>(edges, eattr, out, ne);
    }
}

// Round 5
// 429.297 us; speedup vs baseline: 2.3029x; 1.4905x over previous
//
#include <hip/hip_runtime.h>

// VertexUpdate: out[i] = (b_i, x_i, b_i - sum_{e:src[e]=i} c_e)
//
// R1: device atomicAdd scatter -> 771 us; WRITE 500 MB (16M x 32B sectors).
// R3: per-XCD replicas + workgroup-scope atomics -> identical. Atomics RMW
//     in L2 but miss ~100% (4 MB accumulator vs 4 MB L2 + 192 MB stream).
// R4: radix binning, cursor scatter -> 640 us. Partition WRITE = 455 MB:
//     per-edge 8 B stores land in random buckets, line evicted before the
//     run fills -> one dirty 32 B sector per edge. Occupancy 21%.
// R5: LDS counting-sort per 8192-edge tile. Histogram -> scan -> LDS
//     scatter -> LINEAR copy-out (consecutive threads -> consecutive global
//     addresses within each per-(tile,bucket) run). Write waste only at run
//     boundaries. 1954 blocks x 512 thr, 72 KB LDS -> 2 blocks/CU.

#define BSHIFT 11
#define BSIZE (1 << BSHIFT)      // 2048 vertices per bucket
#define NBUCK_PAD 512            // padded bucket count (real: 489)
#define TILE 8192
#define TPB 512

__global__ __launch_bounds__(TPB, 2)
void vu_partition(const int* __restrict__ src,
                  const float* __restrict__ eattr,
                  unsigned long long* __restrict__ pairs,
                  unsigned int* __restrict__ alloc,
                  int ne, int nbuck, int cap) {
    __shared__ unsigned long long sorted[TILE];   // 64 KB
    __shared__ unsigned int hist[NBUCK_PAD];      // counts -> inclusive scan
    __shared__ unsigned int base_l[NBUCK_PAD];    // exclusive prefix (tile)
    __shared__ unsigned int cursor[NBUCK_PAD];    // scatter cursors
    __shared__ unsigned int gbase[NBUCK_PAD];     // global run base

    int t = threadIdx.x;
    int tile0 = blockIdx.x * TILE;
    int lim = ne - tile0; if (lim > TILE) lim = TILE;

    hist[t] = 0u;                                  // TPB == NBUCK_PAD
    __syncthreads();

    // 1) histogram (src first read: HBM; stays L2-hot for the re-read)
    for (int i = t; i < lim; i += TPB)
        atomicAdd(&hist[src[tile0 + i] >> BSHIFT], 1u);
    __syncthreads();

    unsigned int mycnt = hist[t];
    // 2) inclusive Hillis-Steele scan over 512 entries
    for (int off = 1; off < NBUCK_PAD; off <<= 1) {
        unsigned int v = (t >= off) ? hist[t - off] : 0u;
        __syncthreads();
        hist[t] += v;
        __syncthreads();
    }
    unsigned int excl = hist[t] - mycnt;
    base_l[t] = excl;
    cursor[t] = excl;
    gbase[t] = (t < nbuck && mycnt) ? atomicAdd(&alloc[t], mycnt) : 0u;
    __syncthreads();

    // 3) scatter into LDS, sorted by bucket (re-reads are L2-hot)
    for (int i = t; i < lim; i += TPB) {
        int e = tile0 + i;
        int s = src[e];
        float2 ec = ((const float2*)eattr)[e];     // .y = c_ij
        unsigned int pos = atomicAdd(&cursor[s >> BSHIFT], 1u);
        sorted[pos] =
            ((unsigned long long)__float_as_uint(ec.y) << 32) | (unsigned int)s;
    }
    __syncthreads();

    // 4) linear copy-out: runs are contiguous in both LDS and global
    for (int i = t; i < lim; i += TPB) {
        unsigned long long p = sorted[i];
        unsigned int q = ((unsigned int)p) >> BSHIFT;
        unsigned int dst = q * (unsigned int)cap + gbase[q]
                         + ((unsigned int)i - base_l[q]);
        unsigned int hi = q * (unsigned int)cap + (unsigned int)cap - 1u;
        if (dst > hi) dst = hi;                    // OOB guard (never fires)
        pairs[dst] = p;
    }
}

__global__ __launch_bounds__(1024, 2)
void vu_aggregate(const unsigned long long* __restrict__ pairs,
                  const unsigned int* __restrict__ alloc,
                  const float* __restrict__ vattr,
                  float* __restrict__ out,
                  int nv, int cap) {
    __shared__ float acc[BSIZE];                   // 8 KB
    int q = blockIdx.x;
    int t = threadIdx.x;
    for (int i = t; i < BSIZE; i += 1024) acc[i] = 0.0f;
    __syncthreads();

    unsigned int cnt = alloc[q];
    if (cnt > (unsigned int)cap) cnt = (unsigned int)cap;
    const unsigned long long* p = pairs + (size_t)q * (size_t)cap;
    for (unsigned int i = t; i < cnt; i += 1024) {
        unsigned long long v = p[i];
        atomicAdd(&acc[((unsigned int)v) & (BSIZE - 1)],
                  __uint_as_float((unsigned int)(v >> 32)));
    }
    __syncthreads();

    int v0 = q << BSHIFT;
    for (int i = t; i < BSIZE; i += 1024) {
        int v = v0 + i;
        if (v < nv) {
            float2 va = ((const float2*)vattr)[v]; // .x=b, .y=x
            out[3 * v + 0] = va.x;
            out[3 * v + 1] = va.y;
            out[3 * v + 2] = va.x - acc[i];
        }
    }
}

// ---- fallback (round-1 path, 961 us) if ws is too small ----
__global__ void vu_init_kernel(const float* __restrict__ vattr,
                               float* __restrict__ out, int n) {
    int i = blockIdx.x * blockDim.x + threadIdx.x;
    if (i < n) {
        float2 v = ((const float2*)vattr)[i];
        out[3 * i + 0] = v.x;
        out[3 * i + 1] = v.y;
        out[3 * i + 2] = v.x;
    }
}

__global__ void vu_scatter_kernel(const int* __restrict__ src,
                                  const float* __restrict__ eattr,
                                  float* __restrict__ out, int ne) {
    int t = blockIdx.x * blockDim.x + threadIdx.x;
    int e0 = t * 4;
    if (e0 + 3 < ne) {
        int4 idx = ((const int4*)src)[t];
        float4 a = ((const float4*)eattr)[2 * t + 0];
        float4 b = ((const float4*)eattr)[2 * t + 1];
        atomicAdd(&out[3 * idx.x + 2], -a.y);
        atomicAdd(&out[3 * idx.y + 2], -a.w);
        atomicAdd(&out[3 * idx.z + 2], -b.y);
        atomicAdd(&out[3 * idx.w + 2], -b.w);
    } else {
        for (int e = e0; e < ne; ++e)
            atomicAdd(&out[3 * src[e] + 2], -eattr[2 * e + 1]);
    }
}

extern "C" void kernel_launch(void* const* d_in, const int* in_sizes, int n_in,
                              void* d_out, int out_size, void* d_ws, size_t ws_size,
                              hipStream_t stream) {
    const float* vattr = (const float*)d_in[0];
    const int* edges = (const int*)d_in[1];   // (2, N_E); row 0 = src
    const float* eattr = (const float*)d_in[2];
    float* out = (float*)d_out;

    int nv = in_sizes[0] / 2;   // 1,000,000
    int ne = in_sizes[2] / 2;   // 16,000,000

    int nbuck = (nv + BSIZE - 1) >> BSHIFT;          // 489
    int mean = ne / nbuck;                           // ~32.7K
    int cap = mean + mean / 8 + 1024;                // +~13% slack
    cap = (cap + 15) & ~15;

    size_t alloc_bytes = 4096;
    size_t pair_bytes = (size_t)nbuck * (size_t)cap * 8ull;
    size_t need = alloc_bytes + pair_bytes;          // ~145 MB

    if (ws_size >= need && nbuck <= NBUCK_PAD) {
        unsigned int* alloc = (unsigned int*)d_ws;
        unsigned long long* pairs = (unsigned long long*)((char*)d_ws + alloc_bytes);
        (void)hipMemsetAsync(alloc, 0, (size_t)nbuck * 4, stream);

        int p1_blocks = (ne + TILE - 1) / TILE;      // 1954
        vu_partition<<<p1_blocks, TPB, 0, stream>>>(edges, eattr, pairs, alloc,
                                                    ne, nbuck, cap);
        vu_aggregate<<<nbuck, 1024, 0, stream>>>(pairs, alloc, vattr, out, nv, cap);
    } else {
        int threads = 256;
        int blocks = (nv + threads - 1) / threads;
        vu_init_kernel<<<blocks, threads, 0, stream>>>(vattr, out, nv);
        int nt = (ne + 3) / 4;
        blocks = (nt + threads - 1) / threads;
        vu_scatter_kernel<<<blocks, threads, 0, stream>>>(edges, eattr, out, ne);
    }
}

// Round 6
// 399.963 us; speedup vs baseline: 2.4718x; 1.0733x over previous
//
#include <hip/hip_runtime.h>

// VertexUpdate: out[i] = (b_i, x_i, b_i - sum_{e:src[e]=i} c_e)
//
// R1: device atomicAdd scatter -> 771 us; WRITE 500 MB (16M x 32B sectors).
// R3: per-XCD replicas + wg-scope atomics -> identical (L2 thrash).
// R4: radix binning, cursor scatter -> 640 us (partition WRITE 455 MB).
// R5: LDS counting-sort + linear copy-out -> 429 us. Partition WRITE fixed
//     (149 MB) but 156 us at 21% HBM: latency/occupancy-bound (72 KB LDS x
//     512 thr = 16/32 waves per CU, scalar loads, barrier-serialized).
// R6: TPB 1024 (2 blocks x 16 waves = 32 waves/CU), register-staged int4 /
//     float4 loads (src read ONCE, histogram from registers, high MLP);
//     aggregate: ulonglong2 reads + LDS-staged float4 output.

#define BSHIFT 11
#define BSIZE (1 << BSHIFT)      // 2048 vertices per bucket
#define NBUCK_PAD 512            // padded bucket count (real: 489)
#define TILE 8192
#define TPB 1024

__global__ __launch_bounds__(TPB, 8)
void vu_partition(const int* __restrict__ src,
                  const float* __restrict__ eattr,
                  unsigned long long* __restrict__ pairs,
                  unsigned int* __restrict__ alloc,
                  int ne, int nbuck, int cap) {
    __shared__ unsigned long long sorted[TILE];   // 64 KB
    __shared__ unsigned int hist[NBUCK_PAD];
    __shared__ unsigned int base_l[NBUCK_PAD];
    __shared__ unsigned int cursor[NBUCK_PAD];
    __shared__ unsigned int gbase[NBUCK_PAD];

    int t = threadIdx.x;
    int tile0 = blockIdx.x * TILE;
    int lim = ne - tile0; if (lim > TILE) lim = TILE;
    bool full = (lim == TILE);

    if (t < NBUCK_PAD) hist[t] = 0u;
    __syncthreads();

    // 1) load src into registers (vector, once) + histogram
    int4 sA, sB;
    if (full) {
        const int4* s4 = (const int4*)(src + tile0);
        sA = s4[t];          // edges tile0 + 4t .. +3
        sB = s4[t + TPB];    // edges tile0 + 4096 + 4t .. +3
        atomicAdd(&hist[((unsigned)sA.x) >> BSHIFT], 1u);
        atomicAdd(&hist[((unsigned)sA.y) >> BSHIFT], 1u);
        atomicAdd(&hist[((unsigned)sA.z) >> BSHIFT], 1u);
        atomicAdd(&hist[((unsigned)sA.w) >> BSHIFT], 1u);
        atomicAdd(&hist[((unsigned)sB.x) >> BSHIFT], 1u);
        atomicAdd(&hist[((unsigned)sB.y) >> BSHIFT], 1u);
        atomicAdd(&hist[((unsigned)sB.z) >> BSHIFT], 1u);
        atomicAdd(&hist[((unsigned)sB.w) >> BSHIFT], 1u);
    } else {
        for (int i = t; i < lim; i += TPB)
            atomicAdd(&hist[((unsigned)src[tile0 + i]) >> BSHIFT], 1u);
    }
    __syncthreads();

    unsigned int mycnt = (t < NBUCK_PAD) ? hist[t] : 0u;
    // 2) inclusive Hillis-Steele scan over 512 entries
    for (int off = 1; off < NBUCK_PAD; off <<= 1) {
        unsigned int v = 0u;
        if (t < NBUCK_PAD && t >= off) v = hist[t - off];
        __syncthreads();
        if (t < NBUCK_PAD) hist[t] += v;
        __syncthreads();
    }
    if (t < NBUCK_PAD) {
        unsigned int excl = hist[t] - mycnt;
        base_l[t] = excl;
        cursor[t] = excl;
        gbase[t] = (t < nbuck && mycnt) ? atomicAdd(&alloc[t], mycnt) : 0u;
    }
    __syncthreads();

    // 3) scatter into LDS sorted by bucket (src from registers)
#define VU_SCAT(sv, cv) do { \
        unsigned int q_ = ((unsigned)(sv)) >> BSHIFT; \
        unsigned int pos_ = atomicAdd(&cursor[q_], 1u); \
        sorted[pos_] = ((unsigned long long)__float_as_uint(cv) << 32) \
                       | (unsigned)(sv); } while (0)
    if (full) {
        const float4* ef = (const float4*)eattr;   // 2 edges per float4
        int b0 = (tile0 >> 1) + 2 * t;
        float4 cA0 = ef[b0];
        float4 cA1 = ef[b0 + 1];
        float4 cB0 = ef[b0 + 2048];
        float4 cB1 = ef[b0 + 2049];
        VU_SCAT(sA.x, cA0.y); VU_SCAT(sA.y, cA0.w);
        VU_SCAT(sA.z, cA1.y); VU_SCAT(sA.w, cA1.w);
        VU_SCAT(sB.x, cB0.y); VU_SCAT(sB.y, cB0.w);
        VU_SCAT(sB.z, cB1.y); VU_SCAT(sB.w, cB1.w);
    } else {
        for (int i = t; i < lim; i += TPB) {
            int e = tile0 + i;
            int s = src[e];
            float2 ec = ((const float2*)eattr)[e];
            VU_SCAT(s, ec.y);
        }
    }
#undef VU_SCAT
    __syncthreads();

    // 4) linear copy-out: runs contiguous in LDS and global
    for (int i = t; i < lim; i += TPB) {
        unsigned long long p = sorted[i];
        unsigned int q = ((unsigned int)p) >> BSHIFT;
        unsigned int dst = q * (unsigned int)cap + gbase[q]
                         + ((unsigned int)i - base_l[q]);
        unsigned int hi = q * (unsigned int)cap + (unsigned int)cap - 1u;
        if (dst > hi) dst = hi;                    // OOB guard (never fires)
        pairs[dst] = p;
    }
}

__global__ __launch_bounds__(1024)
void vu_aggregate(const unsigned long long* __restrict__ pairs,
                  const unsigned int* __restrict__ alloc,
                  const float* __restrict__ vattr,
                  float* __restrict__ out,
                  int nv, int cap) {
    __shared__ float acc[BSIZE];                   // 8 KB
    __shared__ float obuf[BSIZE * 3];              // 24 KB
    int q = blockIdx.x;
    int t = threadIdx.x;
    acc[t] = 0.0f;
    acc[t + 1024] = 0.0f;
    __syncthreads();

    unsigned int cnt = alloc[q];
    if (cnt > (unsigned int)cap) cnt = (unsigned int)cap;
    const unsigned long long* p = pairs + (size_t)q * (size_t)cap;
    const ulonglong2* p2 = (const ulonglong2*)p;   // cap mult of 16 -> aligned
    unsigned int n2 = cnt >> 1;
    for (unsigned int i = t; i < n2; i += 1024) {
        ulonglong2 v = p2[i];
        atomicAdd(&acc[((unsigned int)v.x) & (BSIZE - 1)],
                  __uint_as_float((unsigned int)(v.x >> 32)));
        atomicAdd(&acc[((unsigned int)v.y) & (BSIZE - 1)],
                  __uint_as_float((unsigned int)(v.y >> 32)));
    }
    if (t == 0 && (cnt & 1u)) {
        unsigned long long v = p[cnt - 1];
        atomicAdd(&acc[((unsigned int)v) & (BSIZE - 1)],
                  __uint_as_float((unsigned int)(v >> 32)));
    }
    __syncthreads();

    int v0 = q << BSHIFT;
#pragma unroll
    for (int k = 0; k < 2; ++k) {
        int i = t + k * 1024;
        int v = v0 + i;
        if (v < nv) {
            float2 va = ((const float2*)vattr)[v]; // .x=b, .y=x
            obuf[3 * i + 0] = va.x;
            obuf[3 * i + 1] = va.y;
            obuf[3 * i + 2] = va.x - acc[i];
        }
    }
    __syncthreads();

    // coalesced float4 write of the bucket's contiguous out-slice
    long fbase = (long)q * (BSIZE * 3);
    int nfl = 3 * nv - (int)fbase;
    if (nfl > BSIZE * 3) nfl = BSIZE * 3;
    if (nfl > 0) {
        float4* o4 = (float4*)(out + fbase);       // fbase mult of 4
        const float4* s4 = (const float4*)obuf;
        int n4 = nfl >> 2;
        for (int j = t; j < n4; j += 1024) o4[j] = s4[j];
        for (int j = (n4 << 2) + t; j < nfl; j += 1024) out[fbase + j] = obuf[j];
    }
}

// ---- fallback (round-1 path, 961 us) if ws is too small ----
__global__ void vu_init_kernel(const float* __restrict__ vattr,
                               float* __restrict__ out, int n) {
    int i = blockIdx.x * blockDim.x + threadIdx.x;
    if (i < n) {
        float2 v = ((const float2*)vattr)[i];
        out[3 * i + 0] = v.x;
        out[3 * i + 1] = v.y;
        out[3 * i + 2] = v.x;
    }
}

__global__ void vu_scatter_kernel(const int* __restrict__ src,
                                  const float* __restrict__ eattr,
                                  float* __restrict__ out, int ne) {
    int t = blockIdx.x * blockDim.x + threadIdx.x;
    int e0 = t * 4;
    if (e0 + 3 < ne) {
        int4 idx = ((const int4*)src)[t];
        float4 a = ((const float4*)eattr)[2 * t + 0];
        float4 b = ((const float4*)eattr)[2 * t + 1];
        atomicAdd(&out[3 * idx.x + 2], -a.y);
        atomicAdd(&out[3 * idx.y + 2], -a.w);
        atomicAdd(&out[3 * idx.z + 2], -b.y);
        atomicAdd(&out[3 * idx.w + 2], -b.w);
    } else {
        for (int e = e0; e < ne; ++e)
            atomicAdd(&out[3 * src[e] + 2], -eattr[2 * e + 1]);
    }
}

extern "C" void kernel_launch(void* const* d_in, const int* in_sizes, int n_in,
                              void* d_out, int out_size, void* d_ws, size_t ws_size,
                              hipStream_t stream) {
    const float* vattr = (const float*)d_in[0];
    const int* edges = (const int*)d_in[1];   // (2, N_E); row 0 = src
    const float* eattr = (const float*)d_in[2];
    float* out = (float*)d_out;

    int nv = in_sizes[0] / 2;   // 1,000,000
    int ne = in_sizes[2] / 2;   // 16,000,000

    int nbuck = (nv + BSIZE - 1) >> BSHIFT;          // 489
    int mean = ne / nbuck;                           // ~32.7K
    int cap = mean + mean / 8 + 1024;                // +~13% slack
    cap = (cap + 15) & ~15;

    size_t alloc_bytes = 4096;
    size_t pair_bytes = (size_t)nbuck * (size_t)cap * 8ull;
    size_t need = alloc_bytes + pair_bytes;          // ~145 MB

    if (ws_size >= need && nbuck <= NBUCK_PAD) {
        unsigned int* alloc = (unsigned int*)d_ws;
        unsigned long long* pairs = (unsigned long long*)((char*)d_ws + alloc_bytes);
        (void)hipMemsetAsync(alloc, 0, (size_t)nbuck * 4, stream);

        int p1_blocks = (ne + TILE - 1) / TILE;      // 1954
        vu_partition<<<p1_blocks, TPB, 0, stream>>>(edges, eattr, pairs, alloc,
                                                    ne, nbuck, cap);
        vu_aggregate<<<nbuck, 1024, 0, stream>>>(pairs, alloc, vattr, out, nv, cap);
    } else {
        int threads = 256;
        int blocks = (nv + threads - 1) / threads;
        vu_init_kernel<<<blocks, threads, 0, stream>>>(vattr, out, nv);
        int nt = (ne + 3) / 4;
        blocks = (nt + threads - 1) / threads;
        vu_scatter_kernel<<<blocks, threads, 0, stream>>>(edges, eattr, out, ne);
    }
}